// Round 18
// baseline (51.919 us; speedup 1.0000x reference)
//
#include <hip/hip_runtime.h>
#include <hip/hip_bf16.h>

typedef _Float16 f16x8 __attribute__((ext_vector_type(8)));
typedef _Float16 f16x2 __attribute__((ext_vector_type(2)));
typedef float f32x4  __attribute__((ext_vector_type(4)));

#define Bn 4
#define Cn 64
#define Hn 128
#define Wn 128
#define HWn 16384

// ws layout (bytes):
//   xt     [B][H][seg0..7][W][8ch] f16 @ 0   (8 MB)
//   pk_def [18][4][64][8] f16 @ XT_BYTES     B-frags, main conv
//   pk_off [18][3][64][8] f16 @ +PKDEF       B-frags, offset conv
#define XT_BYTES    (Bn*HWn*Cn*2)
#define PKDEF_BYTES (18*4*64*8*2)

static __device__ __forceinline__ unsigned pk_f16(float lo, float hi) {
  union { _Float16 h[2]; unsigned u; } cv;
  cv.h[0] = (_Float16)lo; cv.h[1] = (_Float16)hi;
  return cv.u;
}

// ---- merged: blocks 0..1023 transpose x -> xt (float4 loads); 1024..1055 pack.
__global__ __launch_bounds__(256) void prep_all(const float* __restrict__ x,
                                                const float* __restrict__ w_off,
                                                const float* __restrict__ w_def,
                                                ushort* __restrict__ xt,
                                                ushort* __restrict__ pk_def,
                                                ushort* __restrict__ pk_off) {
  __shared__ float tile[64][68];         // stride 68 f32: 16B-aligned rows
  const int t = threadIdx.x;
  const int blk = blockIdx.x;
  if (blk < 1024) {                      // ---- transpose_cast
    const int b = blk >> 8;
    const int pix0 = (blk & 255) * 64;
    const int y = pix0 >> 7, x0 = pix0 & 127;
    const float* xb = x + (b * Cn) * HWn + pix0;
#pragma unroll
    for (int q = 0; q < 4; ++q) {        // float4 loads: 16B/lane
      int idx = q * 256 + t;             // 1024 slots = 64 rows x 16 float4
      int c = idx >> 4, p4 = idx & 15;
      float4 v = *(const float4*)(xb + c * HWn + p4 * 4);
      *(float4*)&tile[c][p4 * 4] = v;
    }
    __syncthreads();
    const int p = t & 63, cg = t >> 6;
#pragma unroll
    for (int half = 0; half < 2; ++half) {
      const int seg = cg * 2 + half;
      unsigned u[4];
#pragma unroll
      for (int j = 0; j < 4; ++j)
        u[j] = pk_f16(tile[seg * 8 + 2 * j][p], tile[seg * 8 + 2 * j + 1][p]);
      uint4 v = {u[0], u[1], u[2], u[3]};
      *(uint4*)(xt + (((((b << 7) + y) << 3) + seg) * 128 + x0 + p) * 8) = v;
    }
  } else {                               // ---- prep_pack
    const int tt = (blk - 1024) * 256 + t;
    if (tt < 4608) {                     // 18*4*64
      int lane = tt & 63, oc = (tt >> 6) & 3, s = tt >> 8;
      int g = s / 9, k = s % 9;
      int o = oc * 16 + (lane & 15);
      int cb = g * 32 + (lane >> 4) * 8;
      unsigned u[4];
#pragma unroll
      for (int j = 0; j < 4; ++j)
        u[j] = pk_f16(w_def[(o * Cn + cb + 2 * j) * 9 + k],
                      w_def[(o * Cn + cb + 2 * j + 1) * 9 + k]);
      uint4 v = {u[0], u[1], u[2], u[3]};
      *(uint4*)(pk_def + tt * 8) = v;
    } else if (tt < 8064) {              // + 18*3*64
      int t2 = tt - 4608;
      int lane = t2 & 63, r = t2 >> 6;   // r = s*3 + oc
      int oc = r % 3, s = r / 3;
      int k = s >> 1, chalf = s & 1;
      int o = oc * 16 + (lane & 15);
      int cb = chalf * 32 + (lane >> 4) * 8;
      unsigned u[4];
#pragma unroll
      for (int j = 0; j < 4; ++j) {
        float lo = (o < 36) ? w_off[(o * Cn + cb + 2 * j) * 9 + k] : 0.f;
        float hi = (o < 36) ? w_off[(o * Cn + cb + 2 * j + 1) * 9 + k] : 0.f;
        u[j] = pk_f16(lo, hi);
      }
      uint4 v = {u[0], u[1], u[2], u[3]};
      *(uint4*)(pk_off + (r * 64 + lane) * 8) = v;
    }
  }
}

// ---- FUSED (R17) + symmetric epilogue: each gsel-half exchanges only the two
// accumulators its partner finalizes, and writes its own 32 output channels.
#define T_STRIDE (17*25*8)
__global__ __launch_bounds__(1024, 8) void deform_fused(const ushort* __restrict__ xt,
                                                        const ushort* __restrict__ pk_def,
                                                        const ushort* __restrict__ pk_off,
                                                        float* __restrict__ out) {
  __shared__ ushort tile[8 * T_STRIDE];      // 54,400 B (reduce buf aliases later)
  __shared__ _Float16 off_lds[8][36][18];    // 10,368 B
  const int t = threadIdx.x;
  const int lane = t & 63;
  const int wid = t >> 6;                // 0..15
  const int pg = wid >> 1, gsel = wid & 1;
  int bid = blockIdx.x;
  bid = (bid & 7) * 64 + (bid >> 3);     // bijective XCD swizzle (512 % 8 == 0)
  const int b  = bid >> 7;
  const int ty = (bid >> 3) & 15;
  const int tx = bid & 7;
  const int y0t = ty * 8, x0t = tx * 16;
  const int TLY = max(0, y0t - 4), THY = min(127, y0t + 12);
  const int TLX = max(0, x0t - 4), THX = min(127, x0t + 20);
  const int Wd = THX - TLX + 1;
  const int CLO = max(0, y0t - 1), CHI = min(127, y0t + 8);  // P1's row range

  { // stage CORE rows [CLO..CHI] -> LDS (coalesced 16B/lane)
    const int xq = t & 31;
    const int r0 = t >> 5;               // 32 row-groups
    const int nrc = (CHI - CLO + 1) * 8;
    for (int rr = r0; rr < nrc; rr += 32) {
      const int yq = rr >> 3, seg = rr & 7;
      const int gy = CLO + yq;
      if (xq < Wd) {
        const ushort* src = xt + ((((b << 7) + gy) << 3) + seg) * 1024 + (TLX + xq) * 8;
        *(uint4*)&tile[seg * T_STRIDE + ((gy - TLY) * 25 + xq) * 8] = *(const uint4*)src;
      }
    }
  }
  __syncthreads();                       // core ready (vmcnt(0) here, BEFORE halo issue)

  // ---- T14: issue halo-row loads NOW (registers), write to LDS after P1.
  const int nlow = CLO - TLY, nhigh = THY - CHI;
  const int nhalo = (nlow + nhigh) * 8 * 25;   // <= 1400 items of (row, seg, xq)
  uint4 hu0, hu1; int hl0 = -1, hl1 = -1;
  {
    int fi = t;
    if (fi < nhalo) {
      int xq = fi % 25; int r = fi / 25; int seg = r & 7; int hr = r >> 3;
      int gy = (hr < nlow) ? (TLY + hr) : (CHI + 1 + hr - nlow);
      int gx = min(TLX + xq, 127);       // clamped dup cols: never read
      hu0 = *(const uint4*)(xt + ((((b << 7) + gy) << 3) + seg) * 1024 + gx * 8);
      hl0 = seg * T_STRIDE + ((gy - TLY) * 25 + xq) * 8;
    }
    fi = t + 1024;
    if (fi < nhalo) {
      int xq = fi % 25; int r = fi / 25; int seg = r & 7; int hr = r >> 3;
      int gy = (hr < nlow) ? (TLY + hr) : (CHI + 1 + hr - nlow);
      int gx = min(TLX + xq, 127);
      hu1 = *(const uint4*)(xt + ((((b << 7) + gy) << 3) + seg) * 1024 + gx * 8);
      hl1 = seg * T_STRIDE + ((gy - TLY) * 25 + xq) * 8;
    }
  }

  const int h = y0t + pg;
  const int p = lane & 15, kq = lane >> 4;
  const int w_ = x0t + p;
  const int pixin = (h << 7) + x0t;
  const int su = gsel * 4 + kq;
  const int colb = lane & 15;

  // hoisted per-tap data for the regular 3x3 (rows all within CORE)
  int pixoff[9]; bool tvalid[9];
#pragma unroll
  for (int kk = 0; kk < 9; ++kk) {
    int yk = h + kk / 3 - 1, xk = w_ + kk % 3 - 1;
    tvalid[kk] = ((unsigned)yk < 128u) && ((unsigned)xk < 128u);
    int yc = min(max(yk, 0), 127), xc = min(max(xk, 0), 127);
    pixoff[kk] = ((yc - TLY) * 25 + (xc - TLX)) * 8;
  }

  // ---- phase 1: offset conv from staged core rows.
  // N-split: gsel0 -> off ch 0-15; gsel1 -> 16-31 & 32-35.
  {
    f32x4 oa0 = {0,0,0,0}, oa1 = {0,0,0,0}, oa2 = {0,0,0,0};
    const f16x8* pBo = (const f16x8*)pk_off;
#pragma unroll
    for (int s = 0; s < 18; ++s) {
      const int k = s >> 1, chalf = s & 1;
      uint4 t_ = *(const uint4*)&tile[(chalf * 4 + kq) * T_STRIDE + pixoff[k]];
      if (!tvalid[k]) { t_.x = 0; t_.y = 0; t_.z = 0; t_.w = 0; }
      union { uint4 u; f16x8 v; } A; A.u = t_;
      if (gsel == 0) {
        oa0 = __builtin_amdgcn_mfma_f32_16x16x32_f16(A.v, pBo[(s*3 + 0)*64 + lane], oa0, 0,0,0);
      } else {
        oa1 = __builtin_amdgcn_mfma_f32_16x16x32_f16(A.v, pBo[(s*3 + 1)*64 + lane], oa1, 0,0,0);
        oa2 = __builtin_amdgcn_mfma_f32_16x16x32_f16(A.v, pBo[(s*3 + 2)*64 + lane], oa2, 0,0,0);
      }
    }
    // D: col = lane&15 = offset channel (within 16-group), row = kq*4+r = pixel x
    if (gsel == 0) {
#pragma unroll
      for (int r = 0; r < 4; ++r) off_lds[pg][colb][kq * 4 + r] = (_Float16)oa0[r];
    } else {
#pragma unroll
      for (int r = 0; r < 4; ++r) {
        off_lds[pg][16 + colb][kq * 4 + r] = (_Float16)oa1[r];
        if (colb < 4) off_lds[pg][32 + colb][kq * 4 + r] = (_Float16)oa2[r];
      }
    }
  }

  // write the halo rows (loads have been in flight under all of P1)
  if (hl0 >= 0) *(uint4*)&tile[hl0] = hu0;
  if (hl1 >= 0) *(uint4*)&tile[hl1] = hu1;
  __syncthreads();                       // off_lds + full tile ready

  // this wave's 18 offset channels for its pixel (broadcast across kq)
  float offv[18];
#pragma unroll
  for (int j = 0; j < 18; ++j) offv[j] = (float)off_lds[pg][gsel * 18 + j][p];

  // ---- phase 2: deformable gather + packed-f16 bilinear + main MFMA
  f32x4 acc0={0,0,0,0}, acc1={0,0,0,0}, acc2={0,0,0,0}, acc3={0,0,0,0};
  const f16x8* pB = (const f16x8*)pk_def;

#pragma unroll
  for (int j = 0; j < 9; ++j) {
    const int k = j;
    float py = offv[2*j]   + (float)(h  + k / 3 - 1);
    float px = offv[2*j+1] + (float)(w_ + k % 3 - 1);
    float fy = floorf(py), fx = floorf(px);
    int y0 = (int)fy, x0 = (int)fx;
    float dy = py - fy, dx = px - fx;

    bool vy0 = (y0 >= 0) && (y0 < Hn);
    bool vy1 = (y0 >= -1) && (y0 < Hn - 1);
    bool vx0 = (x0 >= 0) && (x0 < Wn);
    bool vx1 = (x0 >= -1) && (x0 < Wn - 1);
    float omdy = 1.f - dy, omdx = 1.f - dx;
    float w00 = (vy0 && vx0) ? omdy * omdx : 0.f;
    float w01 = (vy0 && vx1) ? omdy * dx   : 0.f;
    float w10 = (vy1 && vx0) ? dy * omdx   : 0.f;
    float w11 = (vy1 && vx1) ? dy * dx     : 0.f;

    int iy0 = min(max(y0, 0), Hn - 1), iy1 = min(max(y0 + 1, 0), Hn - 1);
    int ix0 = min(max(x0, 0), Wn - 1), ix1 = min(max(x0 + 1, 0), Wn - 1);

    uint4 c00, c01, c10, c11;
    bool intile = (iy0 >= TLY) && (iy1 <= THY) && (ix0 >= TLX) && (ix1 <= THX);
    if (__all((int)intile)) {            // fast path: LDS (margin 4: ~94% of taps)
      const int base = su * T_STRIDE;
      const int ly0 = iy0 - TLY, ly1 = iy1 - TLY;
      const int lx0 = ix0 - TLX, lx1 = ix1 - TLX;
      c00 = *(const uint4*)&tile[base + (ly0 * 25 + lx0) * 8];
      c01 = *(const uint4*)&tile[base + (ly0 * 25 + lx1) * 8];
      c10 = *(const uint4*)&tile[base + (ly1 * 25 + lx0) * 8];
      c11 = *(const uint4*)&tile[base + (ly1 * 25 + lx1) * 8];
    } else {                             // rare fallback: global gather (L2-hot)
      const int r0g = ((((b << 7) + iy0) << 3) + su) * 128;
      const int r1g = ((((b << 7) + iy1) << 3) + su) * 128;
      c00 = *(const uint4*)(xt + (r0g + ix0) * 8);
      c01 = *(const uint4*)(xt + (r0g + ix1) * 8);
      c10 = *(const uint4*)(xt + (r1g + ix0) * 8);
      c11 = *(const uint4*)(xt + (r1g + ix1) * 8);
    }

    // packed-f16 bilinear: result words ARE the f16 MFMA A-fragment
    const _Float16 h00 = (_Float16)w00, h01 = (_Float16)w01;
    const _Float16 h10 = (_Float16)w10, h11 = (_Float16)w11;
    const f16x2 W00 = {h00, h00}, W01 = {h01, h01};
    const f16x2 W10 = {h10, h10}, W11 = {h11, h11};
    union U32H { unsigned u; f16x2 h; };
    union { uint4 u; f16x8 v; } A;
#define BILC(comp, fld)                                                        \
    { U32H a0, a1, a2, a3, r;                                                  \
      a0.u = c00.comp; a1.u = c01.comp; a2.u = c10.comp; a3.u = c11.comp;      \
      r.h = a0.h * W00 + a1.h * W01 + a2.h * W10 + a3.h * W11;                 \
      A.u.fld = r.u; }
    BILC(x, x) BILC(y, y) BILC(z, z) BILC(w, w)
#undef BILC

    const int s = gsel * 9 + j;
    acc0 = __builtin_amdgcn_mfma_f32_16x16x32_f16(A.v, pB[(s*4 + 0)*64 + lane], acc0, 0,0,0);
    acc1 = __builtin_amdgcn_mfma_f32_16x16x32_f16(A.v, pB[(s*4 + 1)*64 + lane], acc1, 0,0,0);
    acc2 = __builtin_amdgcn_mfma_f32_16x16x32_f16(A.v, pB[(s*4 + 2)*64 + lane], acc2, 0,0,0);
    acc3 = __builtin_amdgcn_mfma_f32_16x16x32_f16(A.v, pB[(s*4 + 3)*64 + lane], acc3, 0,0,0);
  }

  __syncthreads();                       // all waves done with tile
  // symmetric pair-reduce: gsel1 contributes acc0/1, gsel0 contributes acc2/3;
  // each wave then finishes and writes its own 32 of the 64 output channels.
  float* red = (float*)tile;             // [8][4][64][4] f32 (aliases tile)
  if (gsel == 1) {
    *(f32x4*)&red[((pg * 4 + 0) * 64 + lane) * 4] = acc0;
    *(f32x4*)&red[((pg * 4 + 1) * 64 + lane) * 4] = acc1;
  } else {
    *(f32x4*)&red[((pg * 4 + 2) * 64 + lane) * 4] = acc2;
    *(f32x4*)&red[((pg * 4 + 3) * 64 + lane) * 4] = acc3;
  }
  __syncthreads();
  float* ob = out + pixin + kq * 4;
  if (gsel == 0) {
    acc0 += *(const f32x4*)&red[((pg * 4 + 0) * 64 + lane) * 4];
    acc1 += *(const f32x4*)&red[((pg * 4 + 1) * 64 + lane) * 4];
#pragma unroll
    for (int r = 0; r < 4; ++r) {
      ob[((b*64 +      colb) << 14) + r] = acc0[r];
      ob[((b*64 + 16 + colb) << 14) + r] = acc1[r];
    }
  } else {
    acc2 += *(const f32x4*)&red[((pg * 4 + 2) * 64 + lane) * 4];
    acc3 += *(const f32x4*)&red[((pg * 4 + 3) * 64 + lane) * 4];
#pragma unroll
    for (int r = 0; r < 4; ++r) {
      ob[((b*64 + 32 + colb) << 14) + r] = acc2[r];
      ob[((b*64 + 48 + colb) << 14) + r] = acc3[r];
    }
  }
}

extern "C" void kernel_launch(void* const* d_in, const int* in_sizes, int n_in,
                              void* d_out, int out_size, void* d_ws, size_t ws_size,
                              hipStream_t stream) {
  const float* x     = (const float*)d_in[0];
  const float* w_off = (const float*)d_in[1];
  const float* w_def = (const float*)d_in[2];
  float* out = (float*)d_out;

  char* ws = (char*)d_ws;
  ushort* xt     = (ushort*)ws;
  ushort* pk_def = (ushort*)(ws + XT_BYTES);
  ushort* pk_off = (ushort*)(ws + XT_BYTES + PKDEF_BYTES);

  prep_all<<<1056, 256, 0, stream>>>(x, w_off, w_def, xt, pk_def, pk_off);
  deform_fused<<<512, 1024, 0, stream>>>(xt, pk_def, pk_off, out);
}

// Round 19
// 47.086 us; speedup vs baseline: 1.1027x; 1.1027x over previous
//
#include <hip/hip_runtime.h>
#include <hip/hip_bf16.h>

typedef _Float16 f16x8 __attribute__((ext_vector_type(8)));
typedef _Float16 f16x2 __attribute__((ext_vector_type(2)));
typedef float f32x4  __attribute__((ext_vector_type(4)));

#define Bn 4
#define Cn 64
#define Hn 128
#define Wn 128
#define HWn 16384

// ws layout (bytes):
//   xt     [B][H][seg0..7][W][8ch] f16 @ 0   (8 MB)
//   pk_def [18][4][64][8] f16 @ XT_BYTES     B-frags, main conv
//   pk_off [18][3][64][8] f16 @ +PKDEF       B-frags, offset conv
#define XT_BYTES    (Bn*HWn*Cn*2)
#define PKDEF_BYTES (18*4*64*8*2)

static __device__ __forceinline__ unsigned pk_f16(float lo, float hi) {
  union { _Float16 h[2]; unsigned u; } cv;
  cv.h[0] = (_Float16)lo; cv.h[1] = (_Float16)hi;
  return cv.u;
}

// ---- merged: blocks 0..1023 transpose x -> xt (float4 loads); 1024..1055 pack.
__global__ __launch_bounds__(256) void prep_all(const float* __restrict__ x,
                                                const float* __restrict__ w_off,
                                                const float* __restrict__ w_def,
                                                ushort* __restrict__ xt,
                                                ushort* __restrict__ pk_def,
                                                ushort* __restrict__ pk_off) {
  __shared__ float tile[64][68];         // stride 68 f32: 16B-aligned rows
  const int t = threadIdx.x;
  const int blk = blockIdx.x;
  if (blk < 1024) {                      // ---- transpose_cast
    const int b = blk >> 8;
    const int pix0 = (blk & 255) * 64;
    const int y = pix0 >> 7, x0 = pix0 & 127;
    const float* xb = x + (b * Cn) * HWn + pix0;
#pragma unroll
    for (int q = 0; q < 4; ++q) {        // float4 loads: 16B/lane
      int idx = q * 256 + t;             // 1024 slots = 64 rows x 16 float4
      int c = idx >> 4, p4 = idx & 15;
      float4 v = *(const float4*)(xb + c * HWn + p4 * 4);
      *(float4*)&tile[c][p4 * 4] = v;
    }
    __syncthreads();
    const int p = t & 63, cg = t >> 6;
#pragma unroll
    for (int half = 0; half < 2; ++half) {
      const int seg = cg * 2 + half;
      unsigned u[4];
#pragma unroll
      for (int j = 0; j < 4; ++j)
        u[j] = pk_f16(tile[seg * 8 + 2 * j][p], tile[seg * 8 + 2 * j + 1][p]);
      uint4 v = {u[0], u[1], u[2], u[3]};
      *(uint4*)(xt + (((((b << 7) + y) << 3) + seg) * 128 + x0 + p) * 8) = v;
    }
  } else {                               // ---- prep_pack
    const int tt = (blk - 1024) * 256 + t;
    if (tt < 4608) {                     // 18*4*64
      int lane = tt & 63, oc = (tt >> 6) & 3, s = tt >> 8;
      int g = s / 9, k = s % 9;
      int o = oc * 16 + (lane & 15);
      int cb = g * 32 + (lane >> 4) * 8;
      unsigned u[4];
#pragma unroll
      for (int j = 0; j < 4; ++j)
        u[j] = pk_f16(w_def[(o * Cn + cb + 2 * j) * 9 + k],
                      w_def[(o * Cn + cb + 2 * j + 1) * 9 + k]);
      uint4 v = {u[0], u[1], u[2], u[3]};
      *(uint4*)(pk_def + tt * 8) = v;
    } else if (tt < 8064) {              // + 18*3*64
      int t2 = tt - 4608;
      int lane = t2 & 63, r = t2 >> 6;   // r = s*3 + oc
      int oc = r % 3, s = r / 3;
      int k = s >> 1, chalf = s & 1;
      int o = oc * 16 + (lane & 15);
      int cb = chalf * 32 + (lane >> 4) * 8;
      unsigned u[4];
#pragma unroll
      for (int j = 0; j < 4; ++j) {
        float lo = (o < 36) ? w_off[(o * Cn + cb + 2 * j) * 9 + k] : 0.f;
        float hi = (o < 36) ? w_off[(o * Cn + cb + 2 * j + 1) * 9 + k] : 0.f;
        u[j] = pk_f16(lo, hi);
      }
      uint4 v = {u[0], u[1], u[2], u[3]};
      *(uint4*)(pk_off + (r * 64 + lane) * 8) = v;
    }
  }
}

// ---- FUSED (R17 best-known, reverted verbatim): lb(1024,8), x-halo +/-4,
// T14 async halo staging, ASYMMETRIC epilogue (gsel1 stores all 4 accs,
// gsel0 reduces + writes all 64 channels — the faster variant, twice tested).
#define T_STRIDE (17*25*8)
__global__ __launch_bounds__(1024, 8) void deform_fused(const ushort* __restrict__ xt,
                                                        const ushort* __restrict__ pk_def,
                                                        const ushort* __restrict__ pk_off,
                                                        float* __restrict__ out) {
  __shared__ ushort tile[8 * T_STRIDE];      // 54,400 B (reduce buf aliases later)
  __shared__ _Float16 off_lds[8][36][18];    // 10,368 B
  const int t = threadIdx.x;
  const int lane = t & 63;
  const int wid = t >> 6;                // 0..15
  const int pg = wid >> 1, gsel = wid & 1;
  int bid = blockIdx.x;
  bid = (bid & 7) * 64 + (bid >> 3);     // bijective XCD swizzle (512 % 8 == 0)
  const int b  = bid >> 7;
  const int ty = (bid >> 3) & 15;
  const int tx = bid & 7;
  const int y0t = ty * 8, x0t = tx * 16;
  const int TLY = max(0, y0t - 4), THY = min(127, y0t + 12);
  const int TLX = max(0, x0t - 4), THX = min(127, x0t + 20);
  const int Wd = THX - TLX + 1;
  const int CLO = max(0, y0t - 1), CHI = min(127, y0t + 8);  // P1's row range

  { // stage CORE rows [CLO..CHI] -> LDS (coalesced 16B/lane)
    const int xq = t & 31;
    const int r0 = t >> 5;               // 32 row-groups
    const int nrc = (CHI - CLO + 1) * 8;
    for (int rr = r0; rr < nrc; rr += 32) {
      const int yq = rr >> 3, seg = rr & 7;
      const int gy = CLO + yq;
      if (xq < Wd) {
        const ushort* src = xt + ((((b << 7) + gy) << 3) + seg) * 1024 + (TLX + xq) * 8;
        *(uint4*)&tile[seg * T_STRIDE + ((gy - TLY) * 25 + xq) * 8] = *(const uint4*)src;
      }
    }
  }
  __syncthreads();                       // core ready (vmcnt(0) here, BEFORE halo issue)

  // ---- T14: issue halo-row loads NOW (registers), write to LDS after P1.
  const int nlow = CLO - TLY, nhigh = THY - CHI;
  const int nhalo = (nlow + nhigh) * 8 * 25;   // <= 1400 items of (row, seg, xq)
  uint4 hu0, hu1; int hl0 = -1, hl1 = -1;
  {
    int fi = t;
    if (fi < nhalo) {
      int xq = fi % 25; int r = fi / 25; int seg = r & 7; int hr = r >> 3;
      int gy = (hr < nlow) ? (TLY + hr) : (CHI + 1 + hr - nlow);
      int gx = min(TLX + xq, 127);       // clamped dup cols: never read
      hu0 = *(const uint4*)(xt + ((((b << 7) + gy) << 3) + seg) * 1024 + gx * 8);
      hl0 = seg * T_STRIDE + ((gy - TLY) * 25 + xq) * 8;
    }
    fi = t + 1024;
    if (fi < nhalo) {
      int xq = fi % 25; int r = fi / 25; int seg = r & 7; int hr = r >> 3;
      int gy = (hr < nlow) ? (TLY + hr) : (CHI + 1 + hr - nlow);
      int gx = min(TLX + xq, 127);
      hu1 = *(const uint4*)(xt + ((((b << 7) + gy) << 3) + seg) * 1024 + gx * 8);
      hl1 = seg * T_STRIDE + ((gy - TLY) * 25 + xq) * 8;
    }
  }

  const int h = y0t + pg;
  const int p = lane & 15, kq = lane >> 4;
  const int w_ = x0t + p;
  const int pixin = (h << 7) + x0t;
  const int su = gsel * 4 + kq;
  const int colb = lane & 15;

  // hoisted per-tap data for the regular 3x3 (rows all within CORE)
  int pixoff[9]; bool tvalid[9];
#pragma unroll
  for (int kk = 0; kk < 9; ++kk) {
    int yk = h + kk / 3 - 1, xk = w_ + kk % 3 - 1;
    tvalid[kk] = ((unsigned)yk < 128u) && ((unsigned)xk < 128u);
    int yc = min(max(yk, 0), 127), xc = min(max(xk, 0), 127);
    pixoff[kk] = ((yc - TLY) * 25 + (xc - TLX)) * 8;
  }

  // ---- phase 1: offset conv from staged core rows.
  // N-split: gsel0 -> off ch 0-15; gsel1 -> 16-31 & 32-35.
  {
    f32x4 oa0 = {0,0,0,0}, oa1 = {0,0,0,0}, oa2 = {0,0,0,0};
    const f16x8* pBo = (const f16x8*)pk_off;
#pragma unroll
    for (int s = 0; s < 18; ++s) {
      const int k = s >> 1, chalf = s & 1;
      uint4 t_ = *(const uint4*)&tile[(chalf * 4 + kq) * T_STRIDE + pixoff[k]];
      if (!tvalid[k]) { t_.x = 0; t_.y = 0; t_.z = 0; t_.w = 0; }
      union { uint4 u; f16x8 v; } A; A.u = t_;
      if (gsel == 0) {
        oa0 = __builtin_amdgcn_mfma_f32_16x16x32_f16(A.v, pBo[(s*3 + 0)*64 + lane], oa0, 0,0,0);
      } else {
        oa1 = __builtin_amdgcn_mfma_f32_16x16x32_f16(A.v, pBo[(s*3 + 1)*64 + lane], oa1, 0,0,0);
        oa2 = __builtin_amdgcn_mfma_f32_16x16x32_f16(A.v, pBo[(s*3 + 2)*64 + lane], oa2, 0,0,0);
      }
    }
    // D: col = lane&15 = offset channel (within 16-group), row = kq*4+r = pixel x
    if (gsel == 0) {
#pragma unroll
      for (int r = 0; r < 4; ++r) off_lds[pg][colb][kq * 4 + r] = (_Float16)oa0[r];
    } else {
#pragma unroll
      for (int r = 0; r < 4; ++r) {
        off_lds[pg][16 + colb][kq * 4 + r] = (_Float16)oa1[r];
        if (colb < 4) off_lds[pg][32 + colb][kq * 4 + r] = (_Float16)oa2[r];
      }
    }
  }

  // write the halo rows (loads have been in flight under all of P1)
  if (hl0 >= 0) *(uint4*)&tile[hl0] = hu0;
  if (hl1 >= 0) *(uint4*)&tile[hl1] = hu1;
  __syncthreads();                       // off_lds + full tile ready

  // this wave's 18 offset channels for its pixel (broadcast across kq)
  float offv[18];
#pragma unroll
  for (int j = 0; j < 18; ++j) offv[j] = (float)off_lds[pg][gsel * 18 + j][p];

  // ---- phase 2: deformable gather + packed-f16 bilinear + main MFMA
  f32x4 acc0={0,0,0,0}, acc1={0,0,0,0}, acc2={0,0,0,0}, acc3={0,0,0,0};
  const f16x8* pB = (const f16x8*)pk_def;

#pragma unroll
  for (int j = 0; j < 9; ++j) {
    const int k = j;
    float py = offv[2*j]   + (float)(h  + k / 3 - 1);
    float px = offv[2*j+1] + (float)(w_ + k % 3 - 1);
    float fy = floorf(py), fx = floorf(px);
    int y0 = (int)fy, x0 = (int)fx;
    float dy = py - fy, dx = px - fx;

    bool vy0 = (y0 >= 0) && (y0 < Hn);
    bool vy1 = (y0 >= -1) && (y0 < Hn - 1);
    bool vx0 = (x0 >= 0) && (x0 < Wn);
    bool vx1 = (x0 >= -1) && (x0 < Wn - 1);
    float omdy = 1.f - dy, omdx = 1.f - dx;
    float w00 = (vy0 && vx0) ? omdy * omdx : 0.f;
    float w01 = (vy0 && vx1) ? omdy * dx   : 0.f;
    float w10 = (vy1 && vx0) ? dy * omdx   : 0.f;
    float w11 = (vy1 && vx1) ? dy * dx     : 0.f;

    int iy0 = min(max(y0, 0), Hn - 1), iy1 = min(max(y0 + 1, 0), Hn - 1);
    int ix0 = min(max(x0, 0), Wn - 1), ix1 = min(max(x0 + 1, 0), Wn - 1);

    uint4 c00, c01, c10, c11;
    bool intile = (iy0 >= TLY) && (iy1 <= THY) && (ix0 >= TLX) && (ix1 <= THX);
    if (__all((int)intile)) {            // fast path: LDS (margin 4: ~94% of taps)
      const int base = su * T_STRIDE;
      const int ly0 = iy0 - TLY, ly1 = iy1 - TLY;
      const int lx0 = ix0 - TLX, lx1 = ix1 - TLX;
      c00 = *(const uint4*)&tile[base + (ly0 * 25 + lx0) * 8];
      c01 = *(const uint4*)&tile[base + (ly0 * 25 + lx1) * 8];
      c10 = *(const uint4*)&tile[base + (ly1 * 25 + lx0) * 8];
      c11 = *(const uint4*)&tile[base + (ly1 * 25 + lx1) * 8];
    } else {                             // rare fallback: global gather (L2-hot)
      const int r0g = ((((b << 7) + iy0) << 3) + su) * 128;
      const int r1g = ((((b << 7) + iy1) << 3) + su) * 128;
      c00 = *(const uint4*)(xt + (r0g + ix0) * 8);
      c01 = *(const uint4*)(xt + (r0g + ix1) * 8);
      c10 = *(const uint4*)(xt + (r1g + ix0) * 8);
      c11 = *(const uint4*)(xt + (r1g + ix1) * 8);
    }

    // packed-f16 bilinear: result words ARE the f16 MFMA A-fragment
    const _Float16 h00 = (_Float16)w00, h01 = (_Float16)w01;
    const _Float16 h10 = (_Float16)w10, h11 = (_Float16)w11;
    const f16x2 W00 = {h00, h00}, W01 = {h01, h01};
    const f16x2 W10 = {h10, h10}, W11 = {h11, h11};
    union U32H { unsigned u; f16x2 h; };
    union { uint4 u; f16x8 v; } A;
#define BILC(comp, fld)                                                        \
    { U32H a0, a1, a2, a3, r;                                                  \
      a0.u = c00.comp; a1.u = c01.comp; a2.u = c10.comp; a3.u = c11.comp;      \
      r.h = a0.h * W00 + a1.h * W01 + a2.h * W10 + a3.h * W11;                 \
      A.u.fld = r.u; }
    BILC(x, x) BILC(y, y) BILC(z, z) BILC(w, w)
#undef BILC

    const int s = gsel * 9 + j;
    acc0 = __builtin_amdgcn_mfma_f32_16x16x32_f16(A.v, pB[(s*4 + 0)*64 + lane], acc0, 0,0,0);
    acc1 = __builtin_amdgcn_mfma_f32_16x16x32_f16(A.v, pB[(s*4 + 1)*64 + lane], acc1, 0,0,0);
    acc2 = __builtin_amdgcn_mfma_f32_16x16x32_f16(A.v, pB[(s*4 + 2)*64 + lane], acc2, 0,0,0);
    acc3 = __builtin_amdgcn_mfma_f32_16x16x32_f16(A.v, pB[(s*4 + 3)*64 + lane], acc3, 0,0,0);
  }

  __syncthreads();                       // all waves done with tile
  float* red = (float*)tile;             // [8][4][64][4] f32 = 32 KB (aliases tile)
  if (gsel == 1) {
    *(f32x4*)&red[((pg * 4 + 0) * 64 + lane) * 4] = acc0;
    *(f32x4*)&red[((pg * 4 + 1) * 64 + lane) * 4] = acc1;
    *(f32x4*)&red[((pg * 4 + 2) * 64 + lane) * 4] = acc2;
    *(f32x4*)&red[((pg * 4 + 3) * 64 + lane) * 4] = acc3;
  }
  __syncthreads();
  if (gsel == 0) {
    acc0 += *(const f32x4*)&red[((pg * 4 + 0) * 64 + lane) * 4];
    acc1 += *(const f32x4*)&red[((pg * 4 + 1) * 64 + lane) * 4];
    acc2 += *(const f32x4*)&red[((pg * 4 + 2) * 64 + lane) * 4];
    acc3 += *(const f32x4*)&red[((pg * 4 + 3) * 64 + lane) * 4];
    float* ob = out + pixin + kq * 4;
#pragma unroll
    for (int r = 0; r < 4; ++r) {
      ob[((b*64 +      colb) << 14) + r] = acc0[r];
      ob[((b*64 + 16 + colb) << 14) + r] = acc1[r];
      ob[((b*64 + 32 + colb) << 14) + r] = acc2[r];
      ob[((b*64 + 48 + colb) << 14) + r] = acc3[r];
    }
  }
}

extern "C" void kernel_launch(void* const* d_in, const int* in_sizes, int n_in,
                              void* d_out, int out_size, void* d_ws, size_t ws_size,
                              hipStream_t stream) {
  const float* x     = (const float*)d_in[0];
  const float* w_off = (const float*)d_in[1];
  const float* w_def = (const float*)d_in[2];
  float* out = (float*)d_out;

  char* ws = (char*)d_ws;
  ushort* xt     = (ushort*)ws;
  ushort* pk_def = (ushort*)(ws + XT_BYTES);
  ushort* pk_off = (ushort*)(ws + XT_BYTES + PKDEF_BYTES);

  prep_all<<<1056, 256, 0, stream>>>(x, w_off, w_def, xt, pk_def, pk_off);
  deform_fused<<<512, 1024, 0, stream>>>(xt, pk_def, pk_off, out);
}

// Round 20
// 46.573 us; speedup vs baseline: 1.1148x; 1.0110x over previous
//
#include <hip/hip_runtime.h>
#include <hip/hip_bf16.h>

typedef _Float16 f16x8 __attribute__((ext_vector_type(8)));
typedef _Float16 f16x2 __attribute__((ext_vector_type(2)));
typedef float f32x4  __attribute__((ext_vector_type(4)));

#define Bn 4
#define Cn 64
#define Hn 128
#define Wn 128
#define HWn 16384

// ws layout (bytes):
//   xt     [B][H][seg0..7][W][8ch] f16 @ 0   (8 MB)
//   pk_def [18][4][64][8] f16 @ XT_BYTES     B-frags, main conv
//   pk_off [18][3][64][8] f16 @ +PKDEF       B-frags, offset conv
#define XT_BYTES    (Bn*HWn*Cn*2)
#define PKDEF_BYTES (18*4*64*8*2)

static __device__ __forceinline__ unsigned pk_f16(float lo, float hi) {
  union { _Float16 h[2]; unsigned u; } cv;
  cv.h[0] = (_Float16)lo; cv.h[1] = (_Float16)hi;
  return cv.u;
}

static __device__ __forceinline__ void gload16(const ushort* g, ushort* l) {
  __builtin_amdgcn_global_load_lds(
      (const __attribute__((address_space(1))) void*)g,
      (__attribute__((address_space(3))) void*)l, 16, 0, 0);
}

// ---- merged: blocks 0..1023 transpose x -> xt (float4 loads); 1024..1055 pack.
__global__ __launch_bounds__(256) void prep_all(const float* __restrict__ x,
                                                const float* __restrict__ w_off,
                                                const float* __restrict__ w_def,
                                                ushort* __restrict__ xt,
                                                ushort* __restrict__ pk_def,
                                                ushort* __restrict__ pk_off) {
  __shared__ float tile[64][68];         // stride 68 f32: 16B-aligned rows
  const int t = threadIdx.x;
  const int blk = blockIdx.x;
  if (blk < 1024) {                      // ---- transpose_cast
    const int b = blk >> 8;
    const int pix0 = (blk & 255) * 64;
    const int y = pix0 >> 7, x0 = pix0 & 127;
    const float* xb = x + (b * Cn) * HWn + pix0;
#pragma unroll
    for (int q = 0; q < 4; ++q) {        // float4 loads: 16B/lane
      int idx = q * 256 + t;             // 1024 slots = 64 rows x 16 float4
      int c = idx >> 4, p4 = idx & 15;
      float4 v = *(const float4*)(xb + c * HWn + p4 * 4);
      *(float4*)&tile[c][p4 * 4] = v;
    }
    __syncthreads();
    const int p = t & 63, cg = t >> 6;
#pragma unroll
    for (int half = 0; half < 2; ++half) {
      const int seg = cg * 2 + half;
      unsigned u[4];
#pragma unroll
      for (int j = 0; j < 4; ++j)
        u[j] = pk_f16(tile[seg * 8 + 2 * j][p], tile[seg * 8 + 2 * j + 1][p]);
      uint4 v = {u[0], u[1], u[2], u[3]};
      *(uint4*)(xt + (((((b << 7) + y) << 3) + seg) * 128 + x0 + p) * 8) = v;
    }
  } else {                               // ---- prep_pack
    const int tt = (blk - 1024) * 256 + t;
    if (tt < 4608) {                     // 18*4*64
      int lane = tt & 63, oc = (tt >> 6) & 3, s = tt >> 8;
      int g = s / 9, k = s % 9;
      int o = oc * 16 + (lane & 15);
      int cb = g * 32 + (lane >> 4) * 8;
      unsigned u[4];
#pragma unroll
      for (int j = 0; j < 4; ++j)
        u[j] = pk_f16(w_def[(o * Cn + cb + 2 * j) * 9 + k],
                      w_def[(o * Cn + cb + 2 * j + 1) * 9 + k]);
      uint4 v = {u[0], u[1], u[2], u[3]};
      *(uint4*)(pk_def + tt * 8) = v;
    } else if (tt < 8064) {              // + 18*3*64
      int t2 = tt - 4608;
      int lane = t2 & 63, r = t2 >> 6;   // r = s*3 + oc
      int oc = r % 3, s = r / 3;
      int k = s >> 1, chalf = s & 1;
      int o = oc * 16 + (lane & 15);
      int cb = chalf * 32 + (lane >> 4) * 8;
      unsigned u[4];
#pragma unroll
      for (int j = 0; j < 4; ++j) {
        float lo = (o < 36) ? w_off[(o * Cn + cb + 2 * j) * 9 + k] : 0.f;
        float hi = (o < 36) ? w_off[(o * Cn + cb + 2 * j + 1) * 9 + k] : 0.f;
        u[j] = pk_f16(lo, hi);
      }
      uint4 v = {u[0], u[1], u[2], u[3]};
      *(uint4*)(pk_off + (r * 64 + lane) * 8) = v;
    }
  }
}

// ---- FUSED (R17 structure) with global_load_lds staging:
// whole 17-row tile filled LINEARLY via async global->LDS (wave-uniform LDS
// base + per-lane clamped global source); loads stay in flight to the barrier.
// 54 wave-rounds cover 3456 slots; 896B pad absorbs the 56-slot overshoot.
#define T_STRIDE (17*25*8)
#define TILE_SLOTS 3400                  // uint4 slots actually used
__global__ __launch_bounds__(1024, 8) void deform_fused(const ushort* __restrict__ xt,
                                                        const ushort* __restrict__ pk_def,
                                                        const ushort* __restrict__ pk_off,
                                                        float* __restrict__ out) {
  __shared__ __align__(16) ushort tile[8 * T_STRIDE + 56 * 8];  // 55,296 B
  __shared__ _Float16 off_lds[8][36][18];                       // 10,368 B
  const int t = threadIdx.x;
  const int lane = t & 63;
  const int wid = t >> 6;                // 0..15
  const int pg = wid >> 1, gsel = wid & 1;
  int bid = blockIdx.x;
  bid = (bid & 7) * 64 + (bid >> 3);     // bijective XCD swizzle (512 % 8 == 0)
  const int b  = bid >> 7;
  const int ty = (bid >> 3) & 15;
  const int tx = bid & 7;
  const int y0t = ty * 8, x0t = tx * 16;
  const int TLY = max(0, y0t - 4), THY = min(127, y0t + 12);
  const int TLX = max(0, x0t - 4), THX = min(127, x0t + 20);

  { // async staging: 54 wave-rounds x 64 lanes, linear LDS fill
#pragma unroll
    for (int r = 0; r < 4; ++r) {
      const int m = wid + r * 16;        // wave-round index, wave-uniform
      if (m < 54) {
        const int base = m * 64;
        int L = base + lane;
        if (L >= TILE_SLOTS) L = TILE_SLOTS - 1;   // dup src; dest lands in pad
        const int seg = L / 425;
        const int rem = L - seg * 425;
        const int yq  = rem / 25;
        const int xq  = rem - yq * 25;
        const int gy = min(TLY + yq, 127);         // clamped: unread slots only
        const int gx = min(TLX + xq, 127);
        const ushort* src = xt + ((((b << 7) + gy) << 3) + seg) * 1024 + gx * 8;
        gload16(src, tile + base * 8);   // HW: lds[base*8 + lane*8ush] <- src
      }
    }
  }
  __syncthreads();                       // drains vmcnt: full tile ready

  const int h = y0t + pg;
  const int p = lane & 15, kq = lane >> 4;
  const int w_ = x0t + p;
  const int pixin = (h << 7) + x0t;
  const int su = gsel * 4 + kq;
  const int colb = lane & 15;

  // hoisted per-tap data for the regular 3x3
  int pixoff[9]; bool tvalid[9];
#pragma unroll
  for (int kk = 0; kk < 9; ++kk) {
    int yk = h + kk / 3 - 1, xk = w_ + kk % 3 - 1;
    tvalid[kk] = ((unsigned)yk < 128u) && ((unsigned)xk < 128u);
    int yc = min(max(yk, 0), 127), xc = min(max(xk, 0), 127);
    pixoff[kk] = ((yc - TLY) * 25 + (xc - TLX)) * 8;
  }

  // ---- phase 1: offset conv from staged tile.
  // N-split: gsel0 -> off ch 0-15; gsel1 -> 16-31 & 32-35.
  {
    f32x4 oa0 = {0,0,0,0}, oa1 = {0,0,0,0}, oa2 = {0,0,0,0};
    const f16x8* pBo = (const f16x8*)pk_off;
#pragma unroll
    for (int s = 0; s < 18; ++s) {
      const int k = s >> 1, chalf = s & 1;
      uint4 t_ = *(const uint4*)&tile[(chalf * 4 + kq) * T_STRIDE + pixoff[k]];
      if (!tvalid[k]) { t_.x = 0; t_.y = 0; t_.z = 0; t_.w = 0; }
      union { uint4 u; f16x8 v; } A; A.u = t_;
      if (gsel == 0) {
        oa0 = __builtin_amdgcn_mfma_f32_16x16x32_f16(A.v, pBo[(s*3 + 0)*64 + lane], oa0, 0,0,0);
      } else {
        oa1 = __builtin_amdgcn_mfma_f32_16x16x32_f16(A.v, pBo[(s*3 + 1)*64 + lane], oa1, 0,0,0);
        oa2 = __builtin_amdgcn_mfma_f32_16x16x32_f16(A.v, pBo[(s*3 + 2)*64 + lane], oa2, 0,0,0);
      }
    }
    // D: col = lane&15 = offset channel (within 16-group), row = kq*4+r = pixel x
    if (gsel == 0) {
#pragma unroll
      for (int r = 0; r < 4; ++r) off_lds[pg][colb][kq * 4 + r] = (_Float16)oa0[r];
    } else {
#pragma unroll
      for (int r = 0; r < 4; ++r) {
        off_lds[pg][16 + colb][kq * 4 + r] = (_Float16)oa1[r];
        if (colb < 4) off_lds[pg][32 + colb][kq * 4 + r] = (_Float16)oa2[r];
      }
    }
  }
  __syncthreads();                       // off_lds ready

  // this wave's 18 offset channels for its pixel (broadcast across kq)
  float offv[18];
#pragma unroll
  for (int j = 0; j < 18; ++j) offv[j] = (float)off_lds[pg][gsel * 18 + j][p];

  // ---- phase 2: deformable gather + packed-f16 bilinear + main MFMA
  f32x4 acc0={0,0,0,0}, acc1={0,0,0,0}, acc2={0,0,0,0}, acc3={0,0,0,0};
  const f16x8* pB = (const f16x8*)pk_def;

#pragma unroll
  for (int j = 0; j < 9; ++j) {
    const int k = j;
    float py = offv[2*j]   + (float)(h  + k / 3 - 1);
    float px = offv[2*j+1] + (float)(w_ + k % 3 - 1);
    float fy = floorf(py), fx = floorf(px);
    int y0 = (int)fy, x0 = (int)fx;
    float dy = py - fy, dx = px - fx;

    bool vy0 = (y0 >= 0) && (y0 < Hn);
    bool vy1 = (y0 >= -1) && (y0 < Hn - 1);
    bool vx0 = (x0 >= 0) && (x0 < Wn);
    bool vx1 = (x0 >= -1) && (x0 < Wn - 1);
    float omdy = 1.f - dy, omdx = 1.f - dx;
    float w00 = (vy0 && vx0) ? omdy * omdx : 0.f;
    float w01 = (vy0 && vx1) ? omdy * dx   : 0.f;
    float w10 = (vy1 && vx0) ? dy * omdx   : 0.f;
    float w11 = (vy1 && vx1) ? dy * dx     : 0.f;

    int iy0 = min(max(y0, 0), Hn - 1), iy1 = min(max(y0 + 1, 0), Hn - 1);
    int ix0 = min(max(x0, 0), Wn - 1), ix1 = min(max(x0 + 1, 0), Wn - 1);

    uint4 c00, c01, c10, c11;
    bool intile = (iy0 >= TLY) && (iy1 <= THY) && (ix0 >= TLX) && (ix1 <= THX);
    if (__all((int)intile)) {            // fast path: LDS (margin 4: ~94% of taps)
      const int base = su * T_STRIDE;
      const int ly0 = iy0 - TLY, ly1 = iy1 - TLY;
      const int lx0 = ix0 - TLX, lx1 = ix1 - TLX;
      c00 = *(const uint4*)&tile[base + (ly0 * 25 + lx0) * 8];
      c01 = *(const uint4*)&tile[base + (ly0 * 25 + lx1) * 8];
      c10 = *(const uint4*)&tile[base + (ly1 * 25 + lx0) * 8];
      c11 = *(const uint4*)&tile[base + (ly1 * 25 + lx1) * 8];
    } else {                             // rare fallback: global gather (L2-hot)
      const int r0g = ((((b << 7) + iy0) << 3) + su) * 128;
      const int r1g = ((((b << 7) + iy1) << 3) + su) * 128;
      c00 = *(const uint4*)(xt + (r0g + ix0) * 8);
      c01 = *(const uint4*)(xt + (r0g + ix1) * 8);
      c10 = *(const uint4*)(xt + (r1g + ix0) * 8);
      c11 = *(const uint4*)(xt + (r1g + ix1) * 8);
    }

    // packed-f16 bilinear: result words ARE the f16 MFMA A-fragment
    const _Float16 h00 = (_Float16)w00, h01 = (_Float16)w01;
    const _Float16 h10 = (_Float16)w10, h11 = (_Float16)w11;
    const f16x2 W00 = {h00, h00}, W01 = {h01, h01};
    const f16x2 W10 = {h10, h10}, W11 = {h11, h11};
    union U32H { unsigned u; f16x2 h; };
    union { uint4 u; f16x8 v; } A;
#define BILC(comp, fld)                                                        \
    { U32H a0, a1, a2, a3, r;                                                  \
      a0.u = c00.comp; a1.u = c01.comp; a2.u = c10.comp; a3.u = c11.comp;      \
      r.h = a0.h * W00 + a1.h * W01 + a2.h * W10 + a3.h * W11;                 \
      A.u.fld = r.u; }
    BILC(x, x) BILC(y, y) BILC(z, z) BILC(w, w)
#undef BILC

    const int s = gsel * 9 + j;
    acc0 = __builtin_amdgcn_mfma_f32_16x16x32_f16(A.v, pB[(s*4 + 0)*64 + lane], acc0, 0,0,0);
    acc1 = __builtin_amdgcn_mfma_f32_16x16x32_f16(A.v, pB[(s*4 + 1)*64 + lane], acc1, 0,0,0);
    acc2 = __builtin_amdgcn_mfma_f32_16x16x32_f16(A.v, pB[(s*4 + 2)*64 + lane], acc2, 0,0,0);
    acc3 = __builtin_amdgcn_mfma_f32_16x16x32_f16(A.v, pB[(s*4 + 3)*64 + lane], acc3, 0,0,0);
  }

  __syncthreads();                       // all waves done with tile
  float* red = (float*)tile;             // [8][4][64][4] f32 = 32 KB (aliases tile)
  if (gsel == 1) {
    *(f32x4*)&red[((pg * 4 + 0) * 64 + lane) * 4] = acc0;
    *(f32x4*)&red[((pg * 4 + 1) * 64 + lane) * 4] = acc1;
    *(f32x4*)&red[((pg * 4 + 2) * 64 + lane) * 4] = acc2;
    *(f32x4*)&red[((pg * 4 + 3) * 64 + lane) * 4] = acc3;
  }
  __syncthreads();
  if (gsel == 0) {
    acc0 += *(const f32x4*)&red[((pg * 4 + 0) * 64 + lane) * 4];
    acc1 += *(const f32x4*)&red[((pg * 4 + 1) * 64 + lane) * 4];
    acc2 += *(const f32x4*)&red[((pg * 4 + 2) * 64 + lane) * 4];
    acc3 += *(const f32x4*)&red[((pg * 4 + 3) * 64 + lane) * 4];
    float* ob = out + pixin + kq * 4;
#pragma unroll
    for (int r = 0; r < 4; ++r) {
      ob[((b*64 +      colb) << 14) + r] = acc0[r];
      ob[((b*64 + 16 + colb) << 14) + r] = acc1[r];
      ob[((b*64 + 32 + colb) << 14) + r] = acc2[r];
      ob[((b*64 + 48 + colb) << 14) + r] = acc3[r];
    }
  }
}

extern "C" void kernel_launch(void* const* d_in, const int* in_sizes, int n_in,
                              void* d_out, int out_size, void* d_ws, size_t ws_size,
                              hipStream_t stream) {
  const float* x     = (const float*)d_in[0];
  const float* w_off = (const float*)d_in[1];
  const float* w_def = (const float*)d_in[2];
  float* out = (float*)d_out;

  char* ws = (char*)d_ws;
  ushort* xt     = (ushort*)ws;
  ushort* pk_def = (ushort*)(ws + XT_BYTES);
  ushort* pk_off = (ushort*)(ws + XT_BYTES + PKDEF_BYTES);

  prep_all<<<1056, 256, 0, stream>>>(x, w_off, w_def, xt, pk_def, pk_off);
  deform_fused<<<512, 1024, 0, stream>>>(xt, pk_def, pk_off, out);
}